// Round 4
// baseline (167.367 us; speedup 1.0000x reference)
//
#include <hip/hip_runtime.h>

typedef _Float16 f16;
typedef _Float16 f16x2 __attribute__((ext_vector_type(2)));
typedef _Float16 f16x4 __attribute__((ext_vector_type(4)));
typedef _Float16 f16x8 __attribute__((ext_vector_type(8)));
typedef float    f32x4 __attribute__((ext_vector_type(4)));
typedef float    f32x16 __attribute__((ext_vector_type(16)));

constexpr int B_ = 2, H_ = 16, T_ = 2048, D_ = 64, R_ = 32, NT = 32;
constexpr int NROW = B_ * H_ * T_;   // 65536 (bh,t) rows

__device__ __forceinline__ f32x4 mfma16(f16x8 a, f16x8 b, f32x4 c) {
  return __builtin_amdgcn_mfma_f32_16x16x32_f16(a, b, c, 0, 0, 0);
}
__device__ __forceinline__ f32x16 mfma32(f16x8 a, f16x8 b, f32x16 c) {
  return __builtin_amdgcn_mfma_f32_32x32x16_f16(a, b, c, 0, 0, 0);
}
__device__ __forceinline__ void ld_lds16(const void* g, void* l) {
  __builtin_amdgcn_global_load_lds(
      (const __attribute__((address_space(1))) unsigned int*)g,
      (__attribute__((address_space(3))) unsigned int*)l, 16, 0, 0);
}

// ---------------- Kernel A: MFMA projections, fully staged I/O ----------------
// qlr[bh][t][r] = f16( (q@Wq)[t][r] * kron[h,r] * log2e/sqrt(32) )
// klr[bh][t][r] = f16( (k@Wk)[t][r] )
// vt [bh][d][t] = f16( v[t][d] ), 16B units XOR-swizzled: unit u=(t&63)>>3 at u^(d&7)
__global__ __launch_bounds__(256) void proj_kernel(
    const float* __restrict__ q, const float* __restrict__ k, const float* __restrict__ v,
    const float* __restrict__ Wq, const float* __restrict__ Wk,
    const float* __restrict__ c1, const float* __restrict__ c2,
    f16* __restrict__ qlr, f16* __restrict__ klr, f16* __restrict__ vt)
{
  __shared__ f16   sv[64 * 65];        // 8.3 KB  [t][d]
  __shared__ float sW[2][64 * 33];     // 16.9 KB [d][r], stride 33 (2-way max)
  __shared__ f16   sO[2][64 * 40];     // 10 KB   [t][r], stride 40 (16B-aligned rows)

  const int tid = threadIdx.x, w = tid >> 6, lane = tid & 63;
  const int l15 = lane & 15, l4 = lane >> 4;
  const int bh = blockIdx.x >> 5, h = bh & (H_ - 1);
  const int t0 = (blockIdx.x & 31) * 64;

  // ---- phase 0: all global loads up front ----
  const float* vb = v + ((size_t)bh * T_ + t0) * D_;
  float4 vld[4];
#pragma unroll
  for (int it = 0; it < 4; ++it) vld[it] = ((const float4*)vb)[it * 256 + tid];

  const int m = t0 + 16 * w + l15;
  const float* qr = q + ((size_t)bh * T_ + m) * D_;
  const float* kr = k + ((size_t)bh * T_ + m) * D_;
  f16x8 aq[2], ak[2];
#pragma unroll
  for (int kc = 0; kc < 2; ++kc) {
    float4 x0 = *(const float4*)(qr + kc * 32 + 8 * l4);
    float4 x1 = *(const float4*)(qr + kc * 32 + 8 * l4 + 4);
    float4 y0 = *(const float4*)(kr + kc * 32 + 8 * l4);
    float4 y1 = *(const float4*)(kr + kc * 32 + 8 * l4 + 4);
    f16x8 A, K;
    A[0]=(f16)x0.x; A[1]=(f16)x0.y; A[2]=(f16)x0.z; A[3]=(f16)x0.w;
    A[4]=(f16)x1.x; A[5]=(f16)x1.y; A[6]=(f16)x1.z; A[7]=(f16)x1.w;
    K[0]=(f16)y0.x; K[1]=(f16)y0.y; K[2]=(f16)y0.z; K[3]=(f16)y0.w;
    K[4]=(f16)y1.x; K[5]=(f16)y1.y; K[6]=(f16)y1.z; K[7]=(f16)y1.w;
    aq[kc] = A; ak[kc] = K;
  }
  // W tiles: coalesced float4 loads, 8 floats/thread each
  const float* Wqh = Wq + (size_t)h * D_ * R_;
  const float* Wkh = Wk + (size_t)h * D_ * R_;
  float4 wq0 = ((const float4*)Wqh)[tid * 2], wq1 = ((const float4*)Wqh)[tid * 2 + 1];
  float4 wk0 = ((const float4*)Wkh)[tid * 2], wk1 = ((const float4*)Wkh)[tid * 2 + 1];

  // ---- phase 1: stage to LDS ----
#pragma unroll
  for (int it = 0; it < 4; ++it) {
    const int i4 = it * 256 + tid, t = i4 >> 4, dq = (i4 & 15) * 4;
    sv[t * 65 + dq    ] = (f16)vld[it].x;
    sv[t * 65 + dq + 1] = (f16)vld[it].y;
    sv[t * 65 + dq + 2] = (f16)vld[it].z;
    sv[t * 65 + dq + 3] = (f16)vld[it].w;
  }
  {
    const int d = tid >> 2, r0 = (tid & 3) * 8;
    float* pq = &sW[0][d * 33 + r0];
    float* pk = &sW[1][d * 33 + r0];
    pq[0]=wq0.x; pq[1]=wq0.y; pq[2]=wq0.z; pq[3]=wq0.w;
    pq[4]=wq1.x; pq[5]=wq1.y; pq[6]=wq1.z; pq[7]=wq1.w;
    pk[0]=wk0.x; pk[1]=wk0.y; pk[2]=wk0.z; pk[3]=wk0.w;
    pk[4]=wk1.x; pk[5]=wk1.y; pk[6]=wk1.z; pk[7]=wk1.w;
  }
  __syncthreads();

  // ---- phase 2: frags from LDS, MFMA, results to sO ----
  const f32x4 z4 = {0.f, 0.f, 0.f, 0.f};
#pragma unroll
  for (int nt = 0; nt < 2; ++nt) {
    const int r = 16 * nt + l15;
    f16x8 bq[2], bk[2];
#pragma unroll
    for (int kc = 0; kc < 2; ++kc)
#pragma unroll
      for (int j2 = 0; j2 < 8; ++j2) {
        const int d = kc * 32 + 8 * l4 + j2;
        bq[kc][j2] = (f16)sW[0][d * 33 + r];
        bk[kc][j2] = (f16)sW[1][d * 33 + r];
      }
    f32x4 accq = mfma16(aq[0], bq[0], z4); accq = mfma16(aq[1], bq[1], accq);
    f32x4 acck = mfma16(ak[0], bk[0], z4); acck = mfma16(ak[1], bk[1], acck);
    const float scl = c1[h * 4 + (r >> 3)] * c2[h * 8 + (r & 7)] *
                      (0.17677669529663687f * 1.4426950408889634f);
#pragma unroll
    for (int i = 0; i < 4; ++i) {
      const int row = 16 * w + 4 * l4 + i;
      sO[0][row * 40 + r] = (f16)(accq[i] * scl);
      sO[1][row * 40 + r] = (f16)acck[i];
    }
  }
  __syncthreads();

  // ---- phase 3: coalesced stores ----
  {
    const int row = tid >> 2, seg = (tid & 3) * 8;
    const size_t g = ((size_t)bh * T_ + t0 + row) * R_ + seg;
    *(f16x8*)(qlr + g) = *(const f16x8*)&sO[0][row * 40 + seg];
    *(f16x8*)(klr + g) = *(const f16x8*)&sO[1][row * 40 + seg];
  }
#pragma unroll
  for (int it = 0; it < 8; ++it) {
    const int idx = it * 256 + tid, d = idx >> 5, t = (idx & 31) * 2;
    f16x2 pr; pr[0] = sv[t * 65 + d]; pr[1] = sv[(t + 1) * 65 + d];
    const int sw = ((((t >> 3) ^ (d & 7)) << 3) | (t & 7));
    *(f16x2*)(vt + ((size_t)bh * D_ + d) * T_ + t0 + sw) = pr;
  }
}

// ---------------- Kernel B: flash attention, n-split flash-decoding ----------------
__global__ __launch_bounds__(128) void attn_kernel(
    const f16* __restrict__ qlr, const f16* __restrict__ klr,
    const f16* __restrict__ vt, f16* __restrict__ On, float2* __restrict__ ml,
    const int ns_shift)
{
  __shared__ __align__(16) f16 s_k[64 * 32];
  __shared__ __align__(16) f16 s_vt[64 * 64];
  __shared__ __align__(16) f16 s_p[2][32 * 64];

  const int tid = threadIdx.x, w = tid >> 6, lane = tid & 63;
  const int l15 = lane & 15, l4 = lane >> 4, l31 = lane & 31, hh = lane >> 5;
  const int NS = 1 << ns_shift;
  const int bh = blockIdx.x & 31;
  const int rest = blockIdx.x >> 5;
  const int mt = 31 - (rest >> ns_shift);   // longest rows dispatch first
  const int s  = rest & (NS - 1);
  const int m0 = mt * 64;

  const f16x8 aq0 = *(const f16x8*)(qlr + ((size_t)bh * T_ + m0 + 32 * w + l15) * R_ + 8 * l4);
  const f16x8 aq1 = *(const f16x8*)(qlr + ((size_t)bh * T_ + m0 + 32 * w + 16 + l15) * R_ + 8 * l4);

  const f16* kb = klr + (size_t)bh * T_ * R_;
  const f16* vb = vt + (size_t)bh * D_ * T_;

  f32x16 oacc[2];
#pragma unroll
  for (int c = 0; c < 2; ++c)
#pragma unroll
    for (int e = 0; e < 16; ++e) oacc[c][e] = 0.f;
  float mi0 = -1e30f, mi1 = -1e30f, li0 = 0.f, li1 = 0.f;
  const f32x4 z4 = {0.f, 0.f, 0.f, 0.f};

  for (int j = s; j <= mt; j += NS) {
    const int n0 = 64 * j;
    __syncthreads();
#pragma unroll
    for (int e = 0; e < 2; ++e)
      ld_lds16((const char*)kb + (size_t)n0 * 64 + (2 * w + e) * 1024 + lane * 16,
               (char*)s_k + (2 * w + e) * 1024);
#pragma unroll
    for (int e = 0; e < 4; ++e) {
      const int d0 = w * 32 + e * 8;
      ld_lds16((const char*)vb + ((size_t)(d0 + (lane >> 3)) * T_ + n0) * 2 + (lane & 7) * 16,
               (char*)s_vt + d0 * 128);
    }
    __syncthreads();

    f32x4 sc[4][2];
#pragma unroll
    for (int ns = 0; ns < 4; ++ns) {
      f16x8 akf = *(const f16x8*)&s_k[(16 * ns + l15) * 32 + 8 * l4];
      sc[ns][0] = mfma16(akf, aq0, z4);
      sc[ns][1] = mfma16(akf, aq1, z4);
    }
    if (j == mt) {
      const int lim0 = 32 * w + l15;
#pragma unroll
      for (int ns = 0; ns < 4; ++ns) {
        const int nb = 16 * ns + 4 * l4;
#pragma unroll
        for (int i = 0; i < 4; ++i) {
          if (nb + i > lim0)      sc[ns][0][i] = -1e30f;
          if (nb + i > lim0 + 16) sc[ns][1][i] = -1e30f;
        }
      }
    }

    float rm0 = -1e30f, rm1 = -1e30f;
#pragma unroll
    for (int ns = 0; ns < 4; ++ns)
#pragma unroll
      for (int i = 0; i < 4; ++i) {
        rm0 = fmaxf(rm0, sc[ns][0][i]);
        rm1 = fmaxf(rm1, sc[ns][1][i]);
      }
    rm0 = fmaxf(rm0, __shfl_xor(rm0, 16)); rm0 = fmaxf(rm0, __shfl_xor(rm0, 32));
    rm1 = fmaxf(rm1, __shfl_xor(rm1, 16)); rm1 = fmaxf(rm1, __shfl_xor(rm1, 32));
    const float mn0 = fmaxf(mi0, rm0), mn1 = fmaxf(mi1, rm1);
    const float a0 = exp2f(mi0 - mn0), a1 = exp2f(mi1 - mn1);
    float rs0 = 0.f, rs1 = 0.f;
#pragma unroll
    for (int ns = 0; ns < 4; ++ns) {
      f16x4 p0v, p1v;
#pragma unroll
      for (int i = 0; i < 4; ++i) {
        const float p0 = exp2f(sc[ns][0][i] - mn0);
        const float p1 = exp2f(sc[ns][1][i] - mn1);
        rs0 += p0; rs1 += p1;
        p0v[i] = (f16)p0; p1v[i] = (f16)p1;
      }
      const int col = ((((2 * ns + (l4 >> 1)) ^ (l15 & 7)) << 3) | (4 * (l4 & 1)));
      *(f16x4*)&s_p[w][l15 * 64 + col]        = p0v;
      *(f16x4*)&s_p[w][(16 + l15) * 64 + col] = p1v;
    }
    rs0 += __shfl_xor(rs0, 16); rs0 += __shfl_xor(rs0, 32);
    rs1 += __shfl_xor(rs1, 16); rs1 += __shfl_xor(rs1, 32);
    li0 = li0 * a0 + rs0; li1 = li1 * a1 + rs1;
    mi0 = mn0; mi1 = mn1;
    const float aPV = (lane & 16) ? a1 : a0;
#pragma unroll
    for (int c = 0; c < 2; ++c) oacc[c] *= aPV;

#pragma unroll
    for (int kc = 0; kc < 4; ++kc) {
      const int u = (2 * kc + hh) ^ (l31 & 7);
      f16x8 bp = *(const f16x8*)&s_p[w][l31 * 64 + u * 8];
#pragma unroll
      for (int c = 0; c < 2; ++c) {
        f16x8 av = *(const f16x8*)&s_vt[(32 * c + l31) * 64 + u * 8];
        oacc[c] = mfma32(av, bp, oacc[c]);
      }
    }
  }

  const float myl = (lane & 16) ? li1 : li0;
  const float invl = myl > 0.f ? 1.f / myl : 0.f;
  f16* ob = On + (((size_t)s * 32 + bh) * T_ + m0 + 32 * w + l31) * D_;
#pragma unroll
  for (int c = 0; c < 2; ++c)
#pragma unroll
    for (int g = 0; g < 4; ++g) {
      f16x4 o;
#pragma unroll
      for (int e = 0; e < 4; ++e) o[e] = (f16)(oacc[c][4 * g + e] * invl);
      *(f16x4*)(ob + 32 * c + 8 * g + 4 * hh) = o;
    }
  if (l4 < 2) {
    float2 mlv;
    mlv.x = l4 ? mi1 : mi0;
    mlv.y = l4 ? li1 : li0;
    ml[((size_t)s * 32 + bh) * T_ + m0 + 32 * w + 16 * l4 + l15] = mlv;
  }
}

// ---------------- Kernel C: merge n-split partials ----------------
__global__ __launch_bounds__(256) void merge_kernel(
    const f16* __restrict__ On, const float2* __restrict__ ml,
    float* __restrict__ out, const int NS)
{
  const int row = blockIdx.x * 32 + (threadIdx.x >> 3);
  const int d0 = (threadIdx.x & 7) * 8;
  float res[8];
  if (NS == 1) {
    const f16x8 o0 = *(const f16x8*)(On + (size_t)row * 64 + d0);
#pragma unroll
    for (int e = 0; e < 8; ++e) res[e] = (float)o0[e];
  } else {
    float2 mls[4];
    float ms = -3e38f;
    for (int s = 0; s < NS; ++s) {
      mls[s] = ml[(size_t)s * NROW + row];
      ms = fmaxf(ms, mls[s].x);
    }
    float wt[4], wsum = 0.f;
    for (int s = 0; s < NS; ++s) {
      wt[s] = exp2f(mls[s].x - ms) * mls[s].y;
      wsum += wt[s];
    }
    const float inv = 1.f / wsum;
#pragma unroll
    for (int e = 0; e < 8; ++e) res[e] = 0.f;
    for (int s = 0; s < NS; ++s) {
      const f16x8 o = *(const f16x8*)(On + ((size_t)s * NROW + row) * 64 + d0);
      const float c = wt[s] * inv;
#pragma unroll
      for (int e = 0; e < 8; ++e) res[e] += c * (float)o[e];
    }
  }
  float* ob = out + (size_t)row * 64 + d0;
  f32x4 r0, r1;
#pragma unroll
  for (int e = 0; e < 4; ++e) { r0[e] = res[e]; r1[e] = res[4 + e]; }
  *(f32x4*)ob = r0;
  *(f32x4*)(ob + 4) = r1;
}

extern "C" void kernel_launch(void* const* d_in, const int* in_sizes, int n_in,
                              void* d_out, int out_size, void* d_ws, size_t ws_size,
                              hipStream_t stream) {
  const float* q  = (const float*)d_in[0];
  const float* k  = (const float*)d_in[1];
  const float* v  = (const float*)d_in[2];
  const float* Wq = (const float*)d_in[3];
  const float* Wk = (const float*)d_in[4];
  const float* c1 = (const float*)d_in[5];
  const float* c2 = (const float*)d_in[6];
  float* out = (float*)d_out;

  f16* qlr = (f16*)d_ws;                                   // 4 MiB
  f16* klr = qlr + (size_t)B_ * H_ * T_ * R_;              // 4 MiB
  f16* vt  = klr + (size_t)B_ * H_ * T_ * R_;              // 8 MiB
  f16* On  = vt + (size_t)B_ * H_ * T_ * D_;

  const size_t projB = (size_t)16 * 1024 * 1024;
  const size_t perSplit = (size_t)NROW * D_ * 2 + (size_t)NROW * 8;  // On + ml
  int ns_shift = 0;
  if (ws_size >= projB + 4 * perSplit) ns_shift = 2;        // 50 MiB
  else if (ws_size >= projB + 2 * perSplit) ns_shift = 1;   // 33 MiB
  const int NS = 1 << ns_shift;
  float2* ml = (float2*)(On + (size_t)NS * NROW * D_);

  proj_kernel<<<B_ * H_ * NT, 256, 0, stream>>>(q, k, v, Wq, Wk, c1, c2, qlr, klr, vt);
  attn_kernel<<<B_ * H_ * NT * NS, 128, 0, stream>>>(qlr, klr, vt, On, ml, ns_shift);
  merge_kernel<<<NROW / 32, 256, 0, stream>>>(On, ml, out, NS);
}